// Round 4
// baseline (82.830 us; speedup 1.0000x reference)
//
#include <hip/hip_runtime.h>

#define BS 16384
#define D  512
#define MARGIN 1.0f

#define RPW 2                  // rows per wave (keeps live VGPRs <=64 -> 8 waves/SIMD)
#define WPB 4                  // waves per block (256 threads)
#define RPB (RPW * WPB)        // 8 rows per block
#define NBLK (BS / RPB)        // 2048 blocks = 8 blocks/CU

// Stage 1: per-block partial sums of relu(d_ap - d_an + margin).
// RPW=2 keeps register pressure low enough for full occupancy (8 waves/SIMD),
// maximizing TLP to hide random-gather latency; per-wave ILP is 12 float4
// loads in flight. Total outstanding loads per SIMD is unchanged vs RPW=4,
// but twice the wave contexts overlap the FMA + shuffle-reduction tails.
__global__ __launch_bounds__(256) void triplet_partial(
    const float* __restrict__ batch,
    const int*   __restrict__ triplets,
    float* __restrict__ partial)
{
    const int lane = threadIdx.x & 63;
    const int wib  = threadIdx.x >> 6;
    const int rowBase = (blockIdx.x * WPB + wib) * RPW;

    __shared__ float s_part[WPB];

    // Preload indices (wave-uniform -> scalar loads)
    int t0[RPW], t1[RPW], t2[RPW];
    #pragma unroll
    for (int r = 0; r < RPW; ++r) {
        t0[r] = triplets[(rowBase + r) * 3 + 0];
        t1[r] = triplets[(rowBase + r) * 3 + 1];
        t2[r] = triplets[(rowBase + r) * 3 + 2];
    }

    // Issue all loads: 2 rows x 3 ptrs x 2 chunks = 12 float4
    float4 av[RPW][2], pv[RPW][2], nv[RPW][2];
    #pragma unroll
    for (int r = 0; r < RPW; ++r) {
        const float4* __restrict__ a = (const float4*)(batch + (size_t)t0[r] * D);
        const float4* __restrict__ p = (const float4*)(batch + (size_t)t1[r] * D);
        const float4* __restrict__ n = (const float4*)(batch + (size_t)t2[r] * D);
        #pragma unroll
        for (int k = 0; k < 2; ++k) {
            const int j = lane + 64 * k;     // D/4 = 128 float4 per row
            av[r][k] = a[j];
            pv[r][k] = p[j];
            nv[r][k] = n[j];
        }
    }

    // Per-lane partials: sum((a-p)^2 - (a-n)^2), one acc per row
    float acc[RPW];
    #pragma unroll
    for (int r = 0; r < RPW; ++r) {
        float s = 0.0f;
        #pragma unroll
        for (int k = 0; k < 2; ++k) {
            float dp, dn;
            dp = av[r][k].x - pv[r][k].x; dn = av[r][k].x - nv[r][k].x; s += dp * dp - dn * dn;
            dp = av[r][k].y - pv[r][k].y; dn = av[r][k].y - nv[r][k].y; s += dp * dp - dn * dn;
            dp = av[r][k].z - pv[r][k].z; dn = av[r][k].z - nv[r][k].z; s += dp * dp - dn * dn;
            dp = av[r][k].w - pv[r][k].w; dn = av[r][k].w - nv[r][k].w; s += dp * dp - dn * dn;
        }
        acc[r] = s;
    }

    // Interleaved wave reductions: RPW independent ds chains per level
    #pragma unroll
    for (int off = 32; off > 0; off >>= 1) {
        #pragma unroll
        for (int r = 0; r < RPW; ++r)
            acc[r] += __shfl_down(acc[r], off, 64);
    }

    if (lane == 0) {
        float waveLoss = 0.0f;
        #pragma unroll
        for (int r = 0; r < RPW; ++r) {
            const float loss = acc[r] + MARGIN;
            waveLoss += (loss > 0.0f) ? loss : 0.0f;
        }
        s_part[wib] = waveLoss;
    }
    __syncthreads();
    if (threadIdx.x == 0)
        partial[blockIdx.x] = s_part[0] + s_part[1] + s_part[2] + s_part[3];
}

// Stage 2: reduce NBLK (2048) partials -> out[0]. Single block, float4 loads.
__global__ __launch_bounds__(256) void triplet_reduce(
    const float* __restrict__ partial,
    float* __restrict__ out)
{
    const int lane = threadIdx.x & 63;
    const int wib  = threadIdx.x >> 6;

    // 2048 floats = 512 float4, two per thread
    const float4 v0 = ((const float4*)partial)[threadIdx.x];
    const float4 v1 = ((const float4*)partial)[threadIdx.x + 256];
    float acc = (v0.x + v0.y + v0.z + v0.w) + (v1.x + v1.y + v1.z + v1.w);

    #pragma unroll
    for (int off = 32; off > 0; off >>= 1)
        acc += __shfl_down(acc, off, 64);

    __shared__ float s[4];
    if (lane == 0) s[wib] = acc;
    __syncthreads();
    if (threadIdx.x == 0)
        out[0] = s[0] + s[1] + s[2] + s[3];
}

extern "C" void kernel_launch(void* const* d_in, const int* in_sizes, int n_in,
                              void* d_out, int out_size, void* d_ws, size_t ws_size,
                              hipStream_t stream) {
    const float* batch    = (const float*)d_in[0];
    const int*   triplets = (const int*)d_in[1];
    float*       out      = (float*)d_out;
    float*       partial  = (float*)d_ws;    // NBLK floats = 8 KB scratch

    triplet_partial<<<NBLK, 256, 0, stream>>>(batch, triplets, partial);
    triplet_reduce<<<1, 256, 0, stream>>>(partial, out);
}

// Round 5
// 82.223 us; speedup vs baseline: 1.0074x; 1.0074x over previous
//
#include <hip/hip_runtime.h>

#define BS 16384
#define D  512
#define MARGIN 1.0f

#define RPW 4                  // rows per wave — best measured (R2); RPW=2 (more TLP) was neutral->worse
#define WPB 4                  // waves per block (256 threads)
#define RPB (RPW * WPB)        // 16 rows per block
#define NBLK (BS / RPB)        // 1024 blocks

// Stage 1: per-block partial sums of relu(d_ap - d_an + margin).
// (1) preload 12 wave-uniform indices -> row bases in SGPRs; (2) issue all
// 24 float4 loads back-to-back (max outstanding vmem per wave — VMEM queue
// saturation is what sets the ~4.4 TB/s effective gather BW here);
// (3) FMA into 4 independent accumulators; (4) interleave the 4 shuffle
// chains so ds latency overlaps 4-wide.
__global__ __launch_bounds__(256) void triplet_partial(
    const float* __restrict__ batch,
    const int*   __restrict__ triplets,
    float* __restrict__ partial)
{
    const int lane = threadIdx.x & 63;
    const int wib  = threadIdx.x >> 6;
    const int rowBase = (blockIdx.x * WPB + wib) * RPW;

    __shared__ float s_part[WPB];

    int t0[RPW], t1[RPW], t2[RPW];
    #pragma unroll
    for (int r = 0; r < RPW; ++r) {
        t0[r] = triplets[(rowBase + r) * 3 + 0];
        t1[r] = triplets[(rowBase + r) * 3 + 1];
        t2[r] = triplets[(rowBase + r) * 3 + 2];
    }

    float4 av[RPW][2], pv[RPW][2], nv[RPW][2];
    #pragma unroll
    for (int r = 0; r < RPW; ++r) {
        const float4* __restrict__ a = (const float4*)(batch + (size_t)t0[r] * D);
        const float4* __restrict__ p = (const float4*)(batch + (size_t)t1[r] * D);
        const float4* __restrict__ n = (const float4*)(batch + (size_t)t2[r] * D);
        #pragma unroll
        for (int k = 0; k < 2; ++k) {
            const int j = lane + 64 * k;     // D/4 = 128 float4 per row
            av[r][k] = a[j];
            pv[r][k] = p[j];
            nv[r][k] = n[j];
        }
    }

    float acc[RPW];
    #pragma unroll
    for (int r = 0; r < RPW; ++r) {
        float s = 0.0f;
        #pragma unroll
        for (int k = 0; k < 2; ++k) {
            float dp, dn;
            dp = av[r][k].x - pv[r][k].x; dn = av[r][k].x - nv[r][k].x; s += dp * dp - dn * dn;
            dp = av[r][k].y - pv[r][k].y; dn = av[r][k].y - nv[r][k].y; s += dp * dp - dn * dn;
            dp = av[r][k].z - pv[r][k].z; dn = av[r][k].z - nv[r][k].z; s += dp * dp - dn * dn;
            dp = av[r][k].w - pv[r][k].w; dn = av[r][k].w - nv[r][k].w; s += dp * dp - dn * dn;
        }
        acc[r] = s;
    }

    #pragma unroll
    for (int off = 32; off > 0; off >>= 1) {
        #pragma unroll
        for (int r = 0; r < RPW; ++r)
            acc[r] += __shfl_down(acc[r], off, 64);
    }

    if (lane == 0) {
        float waveLoss = 0.0f;
        #pragma unroll
        for (int r = 0; r < RPW; ++r) {
            const float loss = acc[r] + MARGIN;
            waveLoss += (loss > 0.0f) ? loss : 0.0f;
        }
        s_part[wib] = waveLoss;
    }
    __syncthreads();
    if (threadIdx.x == 0)
        partial[blockIdx.x] = s_part[0] + s_part[1] + s_part[2] + s_part[3];
}

// Stage 2: reduce NBLK (1024) partials -> out[0]. Single block, no atomics.
__global__ __launch_bounds__(256) void triplet_reduce(
    const float* __restrict__ partial,
    float* __restrict__ out)
{
    const int lane = threadIdx.x & 63;
    const int wib  = threadIdx.x >> 6;

    // 1024 floats = 256 float4, one per thread
    const float4 v = ((const float4*)partial)[threadIdx.x];
    float acc = v.x + v.y + v.z + v.w;

    #pragma unroll
    for (int off = 32; off > 0; off >>= 1)
        acc += __shfl_down(acc, off, 64);

    __shared__ float s[4];
    if (lane == 0) s[wib] = acc;
    __syncthreads();
    if (threadIdx.x == 0)
        out[0] = s[0] + s[1] + s[2] + s[3];
}

extern "C" void kernel_launch(void* const* d_in, const int* in_sizes, int n_in,
                              void* d_out, int out_size, void* d_ws, size_t ws_size,
                              hipStream_t stream) {
    const float* batch    = (const float*)d_in[0];
    const int*   triplets = (const int*)d_in[1];
    float*       out      = (float*)d_out;
    float*       partial  = (float*)d_ws;    // NBLK floats = 4 KB scratch

    triplet_partial<<<NBLK, 256, 0, stream>>>(batch, triplets, partial);
    triplet_reduce<<<1, 256, 0, stream>>>(partial, out);
}